// Round 1
// baseline (804.015 us; speedup 1.0000x reference)
//
#include <hip/hip_runtime.h>

// GroupingPool2d: x (16,64,384,384) f32 -> out (16,64,192,192) f32
// out[b,c,i,j] = minmax-denormalized product over 2x2 window
//             == window min exactly (product contains an exact 0), but we
//                compute the full formula faithfully — it's free (HBM-bound).

#define EPSF 1e-6f

static constexpr int W_IN  = 384;          // input width
static constexpr int H_IN  = 384;          // input height
static constexpr int WO    = 192;          // output width
static constexpr int HO    = 192;          // output height
static constexpr int PAIRS_PER_ROW = WO / 2;   // 96 float2 stores per output row

__device__ __forceinline__ float window_val(float a, float b, float c, float d) {
    float mn = fminf(fminf(a, b), fminf(c, d));
    float mx = fmaxf(fmaxf(a, b), fmaxf(c, d));
    float rng = mx - mn;
    float inv = 1.0f / (rng + EPSF);
    float p = ((a - mn) * inv) * ((b - mn) * inv) * ((c - mn) * inv) * ((d - mn) * inv);
    return p * rng + mn;   // == mn exactly (one factor is exactly 0)
}

__global__ void grouping_pool2d_kernel(const float* __restrict__ x,
                                       float* __restrict__ out,
                                       int total_pairs) {
    int stride = gridDim.x * blockDim.x;
    for (int t = blockIdx.x * blockDim.x + threadIdx.x; t < total_pairs; t += stride) {
        // t -> (bc, ho, pair): pair covers 2 adjacent windows (4 input cols)
        int row  = t / PAIRS_PER_ROW;              // combined (bc*HO + ho)
        int pair = t - row * PAIRS_PER_ROW;
        int bc   = row / HO;
        int ho   = row - bc * HO;

        const float* src = x + (size_t)bc * (W_IN * H_IN)
                             + (size_t)(2 * ho) * W_IN
                             + (size_t)pair * 4;
        float4 top = *reinterpret_cast<const float4*>(src);            // row 2*ho
        float4 bot = *reinterpret_cast<const float4*>(src + W_IN);     // row 2*ho+1

        float2 res;
        res.x = window_val(top.x, top.y, bot.x, bot.y);
        res.y = window_val(top.z, top.w, bot.z, bot.w);

        float* dst = out + (size_t)bc * (HO * WO) + (size_t)ho * WO + (size_t)pair * 2;
        *reinterpret_cast<float2*>(dst) = res;
    }
}

extern "C" void kernel_launch(void* const* d_in, const int* in_sizes, int n_in,
                              void* d_out, int out_size, void* d_ws, size_t ws_size,
                              hipStream_t stream) {
    const float* x = (const float*)d_in[0];
    float* out = (float*)d_out;

    // total output elems = out_size (16*64*192*192); each thread makes 2
    int total_pairs = out_size / 2;               // 18,874,368
    const int block = 256;
    int grid = (total_pairs + block - 1) / block;
    if (grid > 2048) grid = 2048;                 // grid-stride, ~8 blocks/CU

    grouping_pool2d_kernel<<<grid, block, 0, stream>>>(x, out, total_pairs);
}